// Round 13
// baseline (4219.410 us; speedup 1.0000x reference)
//
#include <hip/hip_runtime.h>

#define N_USERS 50000
#define NTOT    100000
#define D       64
#define NNZ     3200000
#define B       1024
#define SCAN_BLOCKS ((NTOT + 1023) / 1024)   // 98
#define RB     128
#define NB2    ((NTOT + RB - 1) / RB)        // 782 buckets of 128 rows
#define EPB 4096
#define BINA_BLOCKS ((NNZ + EPB - 1) / EPB)  // 782

typedef __attribute__((ext_vector_type(8))) short bf16x8;
typedef __attribute__((ext_vector_type(4))) float f32x4;

__device__ __forceinline__ unsigned short f2bf(float f) {
  unsigned u = __float_as_uint(f);
  unsigned r = (u + 0x7FFFu + ((u >> 16) & 1u)) >> 16;
  return (unsigned short)r;
}
__device__ __forceinline__ float bf2f(unsigned short s) {
  return __uint_as_float(((unsigned)s) << 16);
}

// ---------- bucket-level CSR build (128-row buckets, no per-row ptrs) ----------
__global__ __launch_bounds__(256) void bhist2_kernel(const int* __restrict__ row,
                                                     int* __restrict__ gbh) {
  __shared__ int h[NB2];
  int t = threadIdx.x;
  for (int i = t; i < NB2; i += 256) h[i] = 0;
  __syncthreads();
  int e0 = blockIdx.x * EPB + t;
  #pragma unroll
  for (int i = 0; i < 16; ++i) {
    int e = e0 + i * 256;
    if (e < NNZ) atomicAdd(&h[row[e] >> 7], 1);
  }
  __syncthreads();
  for (int i = t; i < NB2; i += 256) {
    int v = h[i];
    if (v) atomicAdd(&gbh[i], v);
  }
}

__global__ __launch_bounds__(1024) void bscan2_kernel(const int* __restrict__ gbh,
                                                      int* __restrict__ bbase,
                                                      int* __restrict__ bcur) {
  __shared__ int s[1024];
  int t = threadIdx.x;
  int x = (t < NB2) ? gbh[t] : 0;
  s[t] = x;
  __syncthreads();
  #pragma unroll
  for (int st = 1; st < 1024; st <<= 1) {
    int v = (t >= st) ? s[t - st] : 0;
    __syncthreads();
    s[t] += v;
    __syncthreads();
  }
  if (t < NB2) {
    int base = s[t] - x;
    bbase[t] = base;
    bcur[t] = base;
  }
  if (t == 0) bbase[NB2] = NNZ;
}

// Pass A: bucket (r>>7) clustering. temp[pos] = {col | rlow<<17, val}.
__global__ __launch_bounds__(256) void binA2_kernel(
    const int* __restrict__ row, const int* __restrict__ col,
    const float* __restrict__ val, int* __restrict__ bcur,
    int2* __restrict__ temp) {
  __shared__ int hist[NB2];
  __shared__ int base[NB2];
  int t = threadIdx.x;
  for (int i = t; i < NB2; i += 256) hist[i] = 0;
  __syncthreads();
  int e0 = blockIdx.x * EPB + t;
  int xp[16], yb[16], bk[16], ofs[16];
  #pragma unroll
  for (int i = 0; i < 16; ++i) {
    int e = e0 + i * 256;
    bk[i] = -1;
    if (e < NNZ) {
      int r = row[e];
      int b = r >> 7;
      xp[i] = col[e] | ((r & 127) << 17);
      yb[i] = __float_as_int(val[e]);
      bk[i] = b;
      ofs[i] = atomicAdd(&hist[b], 1);
    }
  }
  __syncthreads();
  for (int i = t; i < NB2; i += 256) {
    int h = hist[i];
    base[i] = h ? atomicAdd(&bcur[i], h) : 0;
  }
  __syncthreads();
  #pragma unroll
  for (int i = 0; i < 16; ++i) {
    if (bk[i] >= 0) {
      int2 p; p.x = xp[i]; p.y = yb[i];
      temp[base[bk[i]] + ofs[i]] = p;
    }
  }
}

// Pass B: within each bucket, group edges by column band (col>>9) so all
// blocks sweep the gather table in phase -> L2-resident bands.
__global__ __launch_bounds__(512) void binB3_kernel(
    const int* __restrict__ bbase, const int2* __restrict__ temp,
    int2* __restrict__ epair) {
  __shared__ int cnt[256];
  __shared__ int sc[256];
  __shared__ int cur[256];
  int b = blockIdx.x, t = threadIdx.x;
  int lo = bbase[b], hi = bbase[b + 1];
  if (t < 256) cnt[t] = 0;
  __syncthreads();
  for (int i = lo + t; i < hi; i += 512)
    atomicAdd(&cnt[(temp[i].x & 0x1FFFF) >> 9], 1);
  __syncthreads();
  if (t < 256) sc[t] = cnt[t];
  __syncthreads();
  #pragma unroll
  for (int st = 1; st < 256; st <<= 1) {
    int v = 0;
    if (t < 256 && t >= st) v = sc[t - st];
    __syncthreads();
    if (t < 256) sc[t] += v;
    __syncthreads();
  }
  if (t < 256) cur[t] = lo + sc[t] - cnt[t];
  __syncthreads();
  for (int i = lo + t; i < hi; i += 512) {
    int2 p = temp[i];
    int pos = atomicAdd(&cur[(p.x & 0x1FFFF) >> 9], 1);
    epair[pos] = p;
  }
}

// f32 ego -> bf16 shadow
__global__ __launch_bounds__(256) void tobf_kernel(const float4* __restrict__ src,
                                                   ushort4* __restrict__ dst) {
  int i = blockIdx.x * 256 + threadIdx.x;
  if (i < NTOT * D / 4) {
    float4 f = src[i];
    ushort4 o;
    o.x = f2bf(f.x); o.y = f2bf(f.y); o.z = f2bf(f.z); o.w = f2bf(f.w);
    dst[i] = o;
  }
}

// ---------- SpMM: col-swept edge stream -> LDS f32 accumulators -> MFMA ----------
// Block = 128-row bucket, 512 threads (32 edge-slots x 16 dim-quads).
__global__ __launch_bounds__(512, 6) void spmm_acc_kernel(
    const int* __restrict__ bbase, const int2* __restrict__ epair,
    const unsigned short* __restrict__ bf_in, unsigned short* __restrict__ bf_out,
    const float* __restrict__ Wg, const float* __restrict__ bg,
    const float* __restrict__ Wb, const float* __restrict__ bb) {
  __shared__ float Sacc[RB][65];           // pad 65 -> random-row atomics spread banks
  __shared__ unsigned short sOut[32][68];
  int t = threadIdx.x;
  int b = blockIdx.x;
  int r0 = b * RB;
  int lo = bbase[b], hi = bbase[b + 1];
  for (int i = t; i < RB * 65; i += 512) ((float*)Sacc)[i] = 0.f;
  __syncthreads();

  int s = t >> 4, q = t & 15;
  const ushort4* bfv = (const ushort4*)bf_in;
  for (int base = lo; base < hi; base += 128) {
    int e0 = base + s, e1 = base + 32 + s, e2 = base + 64 + s, e3 = base + 96 + s;
    bool k0 = e0 < hi, k1 = e1 < hi, k2 = e2 < hi, k3 = e3 < hi;
    int2 p0 = epair[k0 ? e0 : lo];
    int2 p1 = epair[k1 ? e1 : lo];
    int2 p2 = epair[k2 ? e2 : lo];
    int2 p3 = epair[k3 ? e3 : lo];
    ushort4 u0 = bfv[(p0.x & 0x1FFFF) * 16 + q];
    ushort4 u1 = bfv[(p1.x & 0x1FFFF) * 16 + q];
    ushort4 u2 = bfv[(p2.x & 0x1FFFF) * 16 + q];
    ushort4 u3 = bfv[(p3.x & 0x1FFFF) * 16 + q];
    float v0 = k0 ? __int_as_float(p0.y) : 0.f;
    float v1 = k1 ? __int_as_float(p1.y) : 0.f;
    float v2 = k2 ? __int_as_float(p2.y) : 0.f;
    float v3 = k3 ? __int_as_float(p3.y) : 0.f;
    int a0 = (p0.x >> 17) & 127, a1 = (p1.x >> 17) & 127;
    int a2 = (p2.x >> 17) & 127, a3 = (p3.x >> 17) & 127;
    int c0 = q * 4;
    atomicAdd(&Sacc[a0][c0 + 0], v0 * bf2f(u0.x));
    atomicAdd(&Sacc[a0][c0 + 1], v0 * bf2f(u0.y));
    atomicAdd(&Sacc[a0][c0 + 2], v0 * bf2f(u0.z));
    atomicAdd(&Sacc[a0][c0 + 3], v0 * bf2f(u0.w));
    atomicAdd(&Sacc[a1][c0 + 0], v1 * bf2f(u1.x));
    atomicAdd(&Sacc[a1][c0 + 1], v1 * bf2f(u1.y));
    atomicAdd(&Sacc[a1][c0 + 2], v1 * bf2f(u1.z));
    atomicAdd(&Sacc[a1][c0 + 3], v1 * bf2f(u1.w));
    atomicAdd(&Sacc[a2][c0 + 0], v2 * bf2f(u2.x));
    atomicAdd(&Sacc[a2][c0 + 1], v2 * bf2f(u2.y));
    atomicAdd(&Sacc[a2][c0 + 2], v2 * bf2f(u2.z));
    atomicAdd(&Sacc[a2][c0 + 3], v2 * bf2f(u2.w));
    atomicAdd(&Sacc[a3][c0 + 0], v3 * bf2f(u3.x));
    atomicAdd(&Sacc[a3][c0 + 1], v3 * bf2f(u3.y));
    atomicAdd(&Sacc[a3][c0 + 2], v3 * bf2f(u3.z));
    atomicAdd(&Sacc[a3][c0 + 3], v3 * bf2f(u3.w));
  }
  __syncthreads();

  // ---- MFMA transform, 4 groups of 32 rows; W frags from global (L1-hot) ----
  int lane = t & 63, w = t >> 6;
  int mt = w & 1, ct = w >> 1;
  int ln = lane & 15, kg = lane >> 4;
  int colg = ct * 16 + ln;
  float bias = bg[colg] + bb[colg];
  bf16x8 bG0, bG1, bB0, bB1;
  {
    const float4* Wg4 = (const float4*)Wg;
    const float4* Wb4 = (const float4*)Wb;
    float4 g0 = Wg4[colg * 16 + kg * 2],     g1 = Wg4[colg * 16 + kg * 2 + 1];
    float4 g2 = Wg4[colg * 16 + 8 + kg * 2], g3 = Wg4[colg * 16 + 8 + kg * 2 + 1];
    float4 b0 = Wb4[colg * 16 + kg * 2],     b1 = Wb4[colg * 16 + kg * 2 + 1];
    float4 b2 = Wb4[colg * 16 + 8 + kg * 2], b3 = Wb4[colg * 16 + 8 + kg * 2 + 1];
    bG0[0]=f2bf(g0.x); bG0[1]=f2bf(g0.y); bG0[2]=f2bf(g0.z); bG0[3]=f2bf(g0.w);
    bG0[4]=f2bf(g1.x); bG0[5]=f2bf(g1.y); bG0[6]=f2bf(g1.z); bG0[7]=f2bf(g1.w);
    bG1[0]=f2bf(g2.x); bG1[1]=f2bf(g2.y); bG1[2]=f2bf(g2.z); bG1[3]=f2bf(g2.w);
    bG1[4]=f2bf(g3.x); bG1[5]=f2bf(g3.y); bG1[6]=f2bf(g3.z); bG1[7]=f2bf(g3.w);
    bB0[0]=f2bf(b0.x); bB0[1]=f2bf(b0.y); bB0[2]=f2bf(b0.z); bB0[3]=f2bf(b0.w);
    bB0[4]=f2bf(b1.x); bB0[5]=f2bf(b1.y); bB0[6]=f2bf(b1.z); bB0[7]=f2bf(b1.w);
    bB1[0]=f2bf(b2.x); bB1[1]=f2bf(b2.y); bB1[2]=f2bf(b2.z); bB1[3]=f2bf(b2.w);
    bB1[4]=f2bf(b3.x); bB1[5]=f2bf(b3.y); bB1[6]=f2bf(b3.z); bB1[7]=f2bf(b3.w);
  }
  #pragma unroll
  for (int g = 0; g < 4; ++g) {
    int ar = g * 32 + mt * 16 + ln;
    int gr = min(r0 + ar, NTOT - 1);       // clamp: S rows of tail bucket are 0
    f32x4 c = {bias, bias, bias, bias};
    bf16x8 aS0, aS1, aH0, aH1;
    #pragma unroll
    for (int j = 0; j < 8; ++j) {
      float sv0 = Sacc[ar][kg * 8 + j];
      float sv1 = Sacc[ar][32 + kg * 8 + j];
      float ev0 = bf2f(bf_in[(size_t)gr * D + kg * 8 + j]);
      float ev1 = bf2f(bf_in[(size_t)gr * D + 32 + kg * 8 + j]);
      aS0[j] = f2bf(sv0); aS1[j] = f2bf(sv1);
      aH0[j] = f2bf(ev0 * sv0); aH1[j] = f2bf(ev1 * sv1);
    }
    c = __builtin_amdgcn_mfma_f32_16x16x32_bf16(aS0, bG0, c, 0, 0, 0);
    c = __builtin_amdgcn_mfma_f32_16x16x32_bf16(aS1, bG1, c, 0, 0, 0);
    c = __builtin_amdgcn_mfma_f32_16x16x32_bf16(aH0, bB0, c, 0, 0, 0);
    c = __builtin_amdgcn_mfma_f32_16x16x32_bf16(aH1, bB1, c, 0, 0, 0);
    #pragma unroll
    for (int j2 = 0; j2 < 4; ++j2)
      sOut[mt * 16 + kg * 4 + j2][colg] = f2bf(c[j2]);
    __syncthreads();
    {
      int rowl = t >> 4, ch = t & 15;
      int gw = r0 + g * 32 + rowl;
      if (gw < NTOT) {
        ushort4 o = *(ushort4*)&sOut[rowl][ch * 4];
        ((ushort4*)&bf_out[(size_t)gw * D])[ch] = o;
      }
    }
    __syncthreads();
  }
}

// ---------- mid-path (f32, per-row hist + scan + scatter) ----------
__global__ __launch_bounds__(256) void hist_kernel(const int* __restrict__ row,
                                                   int* __restrict__ counts) {
  unsigned e = blockIdx.x * 256u + threadIdx.x;
  if (e < NNZ) atomicAdd(&counts[row[e]], 1);
}

__global__ __launch_bounds__(1024) void scanA_kernel(const int* __restrict__ counts,
                                                     int* __restrict__ row_ptr,
                                                     int* __restrict__ blk_sums) {
  __shared__ int s[1024];
  int t = threadIdx.x;
  int gid = blockIdx.x * 1024 + t;
  int x = (gid < NTOT) ? counts[gid] : 0;
  s[t] = x;
  __syncthreads();
  #pragma unroll
  for (int off = 1; off < 1024; off <<= 1) {
    int v = (t >= off) ? s[t - off] : 0;
    __syncthreads();
    s[t] += v;
    __syncthreads();
  }
  if (gid < NTOT) row_ptr[gid] = s[t] - x;
  if (t == 1023) blk_sums[blockIdx.x] = s[t];
}

__global__ __launch_bounds__(128) void scanB_kernel(int* __restrict__ blk_sums,
                                                    int* __restrict__ blk_off) {
  __shared__ int s[128];
  int t = threadIdx.x;
  int x = (t < SCAN_BLOCKS) ? blk_sums[t] : 0;
  s[t] = x;
  __syncthreads();
  #pragma unroll
  for (int off = 1; off < 128; off <<= 1) {
    int v = (t >= off) ? s[t - off] : 0;
    __syncthreads();
    s[t] += v;
    __syncthreads();
  }
  if (t < SCAN_BLOCKS) blk_off[t] = s[t] - x;
}

__global__ __launch_bounds__(1024) void scanC_kernel(int* __restrict__ row_ptr,
                                                     int* __restrict__ cursor,
                                                     const int* __restrict__ blk_off) {
  int gid = blockIdx.x * 1024 + threadIdx.x;
  if (gid < NTOT) {
    int v = row_ptr[gid] + blk_off[blockIdx.x];
    row_ptr[gid] = v;
    cursor[gid] = v;
  }
  if (gid == 0) row_ptr[NTOT] = NNZ;
}

__global__ __launch_bounds__(256) void scatter_kernel(
    const int* __restrict__ row, const int* __restrict__ col,
    const float* __restrict__ val, int* __restrict__ cursor,
    int2* __restrict__ epair) {
  unsigned e = blockIdx.x * 256u + threadIdx.x;
  if (e >= NNZ) return;
  int r = row[e];
  int pos = atomicAdd(&cursor[r], 1);
  int2 p; p.x = col[e]; p.y = __float_as_int(val[e]);
  epair[pos] = p;
}

__global__ __launch_bounds__(1024) void spmm_xform_kernel(
    const int* __restrict__ row_ptr, const int2* __restrict__ epair,
    const float* __restrict__ ego_in, float* __restrict__ ego_out,
    const float* __restrict__ Wg, const float* __restrict__ bg,
    const float* __restrict__ Wb, const float* __restrict__ bb) {
  __shared__ float sWg[64][65];
  __shared__ float sWb[64][65];
  __shared__ float sS[16][64];
  __shared__ float sH[16][64];
  int t = threadIdx.x;
  for (int i = t; i < 4096; i += 1024) {
    sWg[i >> 6][i & 63] = Wg[i];
    sWb[i >> 6][i & 63] = Wb[i];
  }
  __syncthreads();
  int lane = t & 63;
  int w = t >> 6;
  int r = blockIdx.x * 16 + w;
  int rp0 = row_ptr[r], rp1 = row_ptr[r + 1];
  float a0 = 0.f, a1 = 0.f, a2 = 0.f, a3 = 0.f;
  for (int e0 = rp0; e0 < rp1; e0 += 64) {
    int n = rp1 - e0; if (n > 64) n = 64;
    int ce = 0; float ve = 0.f;
    if (lane < n) {
      int2 p = epair[e0 + lane];
      ce = p.x; ve = __int_as_float(p.y);
    }
    int j = 0;
    for (; j + 4 <= n; j += 4) {
      int   c0 = __shfl(ce, j),     c1 = __shfl(ce, j + 1);
      int   c2 = __shfl(ce, j + 2), c3 = __shfl(ce, j + 3);
      float v0 = __shfl(ve, j),     v1 = __shfl(ve, j + 1);
      float v2 = __shfl(ve, j + 2), v3 = __shfl(ve, j + 3);
      float g0 = ego_in[c0 * D + lane], g1 = ego_in[c1 * D + lane];
      float g2 = ego_in[c2 * D + lane], g3 = ego_in[c3 * D + lane];
      a0 = fmaf(v0, g0, a0); a1 = fmaf(v1, g1, a1);
      a2 = fmaf(v2, g2, a2); a3 = fmaf(v3, g3, a3);
    }
    for (; j < n; ++j) {
      int c = __shfl(ce, j); float v = __shfl(ve, j);
      a0 = fmaf(v, ego_in[c * D + lane], a0);
    }
  }
  float s = (a0 + a1) + (a2 + a3);
  float e = ego_in[r * D + lane];
  sS[w][lane] = s;
  sH[w][lane] = e * s;
  float acc = bg[lane] + bb[lane];
  #pragma unroll
  for (int j = 0; j < 64; ++j)
    acc = fmaf(sWg[lane][j], sS[w][j], fmaf(sWb[lane][j], sH[w][j], acc));
  ego_out[r * D + lane] = acc;
}

// ---------- atomic fallback ----------
__global__ __launch_bounds__(256) void spmm_atomic_kernel(
    const int* __restrict__ row, const int* __restrict__ col,
    const float* __restrict__ val, const float* __restrict__ ego,
    float* __restrict__ side) {
  unsigned tid = blockIdx.x * 256u + threadIdx.x;
  unsigned e = tid >> 6, d = tid & 63u;
  if (e >= NNZ) return;
  atomicAdd(&side[row[e] * D + d], val[e] * ego[col[e] * D + d]);
}

__global__ __launch_bounds__(256) void transform_kernel(
    const float* __restrict__ side, float* __restrict__ ego,
    const float* __restrict__ Wg, const float* __restrict__ bg,
    const float* __restrict__ Wb, const float* __restrict__ bb) {
  __shared__ float sWg[64][65];
  __shared__ float sWb[64][65];
  __shared__ float sS[4][64];
  __shared__ float sH[4][64];
  int t = threadIdx.x;
  for (int i = t; i < 4096; i += 256) {
    sWg[i >> 6][i & 63] = Wg[i];
    sWb[i >> 6][i & 63] = Wb[i];
  }
  int w = t >> 6, d = t & 63;
  int r = blockIdx.x * 4 + w;
  float e = 0.f, s = 0.f;
  if (r < NTOT) { e = ego[r * D + d]; s = side[r * D + d]; }
  sS[w][d] = s;
  sH[w][d] = e * s;
  __syncthreads();
  float acc = bg[d] + bb[d];
  #pragma unroll
  for (int j = 0; j < 64; ++j)
    acc = fmaf(sWg[d][j], sS[w][j], fmaf(sWb[d][j], sH[w][j], acc));
  if (r < NTOT) ego[r * D + d] = acc;
}

// ---------- output gathers ----------
__global__ void gather0_kernel(const int* __restrict__ users, const int* __restrict__ pos,
                               const int* __restrict__ neg, const float* __restrict__ ego,
                               float* __restrict__ out) {
  unsigned tid = blockIdx.x * 256u + threadIdx.x;
  unsigned d = tid & 63u, b = (tid >> 6) & 1023u, t = tid >> 16;
  int idx = (t == 0u) ? users[b] : (t == 1u ? N_USERS + pos[b] : N_USERS + neg[b]);
  out[t * (B * 256) + b * 256 + d] = ego[idx * D + d];
}

__global__ void gather_norm_kernel(const int* __restrict__ users, const int* __restrict__ pos,
                                   const int* __restrict__ neg, const float* __restrict__ ego,
                                   float* __restrict__ out, int seg) {
  unsigned tid = blockIdx.x * 256u + threadIdx.x;
  unsigned d = tid & 63u, b = (tid >> 6) & 1023u, t = tid >> 16;
  int idx = (t == 0u) ? users[b] : (t == 1u ? N_USERS + pos[b] : N_USERS + neg[b]);
  float v = ego[idx * D + d];
  float sq = v * v;
  #pragma unroll
  for (int off = 32; off; off >>= 1) sq += __shfl_xor(sq, off);
  float nrm = fmaxf(sqrtf(sq), 1e-12f);
  out[t * (B * 256) + b * 256 + seg * 64 + d] = v / nrm;
}

__global__ void gather_norm_bf_kernel(const int* __restrict__ users, const int* __restrict__ pos,
                                      const int* __restrict__ neg,
                                      const unsigned short* __restrict__ bft,
                                      float* __restrict__ out, int seg) {
  unsigned tid = blockIdx.x * 256u + threadIdx.x;
  unsigned d = tid & 63u, b = (tid >> 6) & 1023u, t = tid >> 16;
  int idx = (t == 0u) ? users[b] : (t == 1u ? N_USERS + pos[b] : N_USERS + neg[b]);
  float v = bf2f(bft[idx * D + d]);
  float sq = v * v;
  #pragma unroll
  for (int off = 32; off; off >>= 1) sq += __shfl_xor(sq, off);
  float nrm = fmaxf(sqrtf(sq), 1e-12f);
  out[t * (B * 256) + b * 256 + seg * 64 + d] = v / nrm;
}

extern "C" void kernel_launch(void* const* d_in, const int* in_sizes, int n_in,
                              void* d_out, int out_size, void* d_ws, size_t ws_size,
                              hipStream_t stream) {
  const int*   users    = (const int*)d_in[0];
  const int*   pos      = (const int*)d_in[1];
  const int*   neg      = (const int*)d_in[2];
  const int*   adj_row  = (const int*)d_in[3];
  const int*   adj_col  = (const int*)d_in[4];
  const float* adj_val  = (const float*)d_in[5];
  const float* user_emb = (const float*)d_in[6];
  const float* item_emb = (const float*)d_in[7];
  const float* gcn_W    = (const float*)d_in[8];
  const float* gcn_b    = (const float*)d_in[9];
  const float* bi_W     = (const float*)d_in[10];
  const float* bi_b     = (const float*)d_in[11];
  float* out = (float*)d_out;

  const size_t EG = (size_t)NTOT * D;

  float* ego0 = (float*)d_ws;
  float* ego1 = ego0 + EG;
  int2*  epair   = (int2*)(ego1 + EG);
  int*   X       = (int*)(epair + NNZ);
  int2*  temp    = (int2*)X;
  unsigned short* bf0 = (unsigned short*)X;
  unsigned short* bf1 = bf0 + EG;
  int*   small   = X + 2 * (size_t)NNZ;
  int*   bcur    = small;                  // NB2
  int*   bbase   = bcur + NB2;             // NB2+1
  int*   gbh     = bbase + (NB2 + 1);      // NB2
  const size_t WS_FULL = ((size_t)(2 * EG + 2 * (size_t)NNZ + 2 * (size_t)NNZ
                          + 3 * NB2 + 1)) * 4;

  int*   m_row_ptr = (int*)(epair + NNZ);
  int*   m_cursor  = m_row_ptr + (NTOT + 1);
  int*   m_blk     = m_cursor + (NTOT + 1);
  int*   m_counts  = (int*)ego1;
  const size_t WS_MID = ((size_t)(2 * EG + 2 * (size_t)NNZ
                         + 2 * (NTOT + 1) + 2 * SCAN_BLOCKS)) * 4;

  hipMemcpyAsync(ego0, user_emb, (size_t)N_USERS * D * sizeof(float),
                 hipMemcpyDeviceToDevice, stream);
  hipMemcpyAsync(ego0 + (size_t)N_USERS * D, item_emb,
                 (size_t)(NTOT - N_USERS) * D * sizeof(float),
                 hipMemcpyDeviceToDevice, stream);

  gather0_kernel<<<768, 256, 0, stream>>>(users, pos, neg, ego0, out);

  if (ws_size >= WS_FULL) {
    hipMemsetAsync(gbh, 0, NB2 * sizeof(int), stream);
    bhist2_kernel<<<BINA_BLOCKS, 256, 0, stream>>>(adj_row, gbh);
    bscan2_kernel<<<1, 1024, 0, stream>>>(gbh, bbase, bcur);
    binA2_kernel<<<BINA_BLOCKS, 256, 0, stream>>>(adj_row, adj_col, adj_val, bcur, temp);
    binB3_kernel<<<NB2, 512, 0, stream>>>(bbase, temp, epair);
    tobf_kernel<<<(NTOT * D / 4 + 255) / 256, 256, 0, stream>>>((const float4*)ego0,
                                                                (ushort4*)bf0);
    unsigned short* bcurr = bf0;
    unsigned short* bnxt  = bf1;
    for (int k = 0; k < 3; ++k) {
      spmm_acc_kernel<<<NB2, 512, 0, stream>>>(
          bbase, epair, bcurr, bnxt,
          gcn_W + k * 4096, gcn_b + k * 64, bi_W + k * 4096, bi_b + k * 64);
      gather_norm_bf_kernel<<<768, 256, 0, stream>>>(users, pos, neg, bnxt, out, k + 1);
      unsigned short* tb = bcurr; bcurr = bnxt; bnxt = tb;
    }
  } else if (ws_size >= WS_MID) {
    hipMemsetAsync(m_counts, 0, (size_t)NTOT * sizeof(int), stream);
    hist_kernel<<<(NNZ + 255) / 256, 256, 0, stream>>>(adj_row, m_counts);
    scanA_kernel<<<SCAN_BLOCKS, 1024, 0, stream>>>(m_counts, m_row_ptr, m_blk);
    scanB_kernel<<<1, 128, 0, stream>>>(m_blk, m_blk + SCAN_BLOCKS);
    scanC_kernel<<<SCAN_BLOCKS, 1024, 0, stream>>>(m_row_ptr, m_cursor, m_blk + SCAN_BLOCKS);
    scatter_kernel<<<(NNZ + 255) / 256, 256, 0, stream>>>(adj_row, adj_col, adj_val,
                                                          m_cursor, epair);
    float* cur = ego0;
    float* nxt = ego1;
    for (int k = 0; k < 3; ++k) {
      spmm_xform_kernel<<<NTOT / 16, 1024, 0, stream>>>(
          m_row_ptr, epair, cur, nxt,
          gcn_W + k * 4096, gcn_b + k * 64, bi_W + k * 4096, bi_b + k * 64);
      gather_norm_kernel<<<768, 256, 0, stream>>>(users, pos, neg, nxt, out, k + 1);
      float* tf = cur; cur = nxt; nxt = tf;
    }
  } else {
    float* side = ego1;
    for (int k = 0; k < 3; ++k) {
      hipMemsetAsync(side, 0, (size_t)NTOT * D * sizeof(float), stream);
      spmm_atomic_kernel<<<(NNZ * 64) / 256, 256, 0, stream>>>(adj_row, adj_col, adj_val,
                                                               ego0, side);
      transform_kernel<<<(NTOT + 3) / 4, 256, 0, stream>>>(
          side, ego0, gcn_W + k * 4096, gcn_b + k * 64, bi_W + k * 4096, bi_b + k * 64);
      gather_norm_kernel<<<768, 256, 0, stream>>>(users, pos, neg, ego0, out, k + 1);
    }
  }
}

// Round 15
// 504.969 us; speedup vs baseline: 8.3558x; 8.3558x over previous
//
#include <hip/hip_runtime.h>

#define N_USERS 50000
#define NTOT    100000
#define D       64
#define NNZ     3200000
#define B       1024
#define SCAN_BLOCKS ((NTOT + 1023) / 1024)   // 98
#define NBUCK ((NTOT + 255) / 256)           // 391
#define EPB 4096
#define BINA_BLOCKS ((NNZ + EPB - 1) / EPB)  // 782

typedef __attribute__((ext_vector_type(8))) short bf16x8;
typedef __attribute__((ext_vector_type(4))) float f32x4;

__device__ __forceinline__ unsigned short f2bf(float f) {
  unsigned u = __float_as_uint(f);
  unsigned r = (u + 0x7FFFu + ((u >> 16) & 1u)) >> 16;
  return (unsigned short)r;
}
__device__ __forceinline__ float bf2f(unsigned short s) {
  return __uint_as_float(((unsigned)s) << 16);
}

// NT 8-byte edge load: (col, val-bits) packed in a u64.
__device__ __forceinline__ void nt_edge(const int2* p, int& c, int& v) {
  unsigned long long u = __builtin_nontemporal_load((const unsigned long long*)p);
  c = (int)(unsigned)(u & 0xFFFFFFFFull);
  v = (int)(unsigned)(u >> 32);
}

// ---------- bucket-level CSR build ----------
__global__ __launch_bounds__(256) void bhist_kernel(const int* __restrict__ row,
                                                    int* __restrict__ gbh) {
  __shared__ int h[NBUCK];
  int t = threadIdx.x;
  for (int i = t; i < NBUCK; i += 256) h[i] = 0;
  __syncthreads();
  int e0 = blockIdx.x * EPB + t;
  #pragma unroll
  for (int i = 0; i < 16; ++i) {
    int e = e0 + i * 256;
    if (e < NNZ) atomicAdd(&h[row[e] >> 8], 1);
  }
  __syncthreads();
  for (int i = t; i < NBUCK; i += 256) {
    int v = h[i];
    if (v) atomicAdd(&gbh[i], v);
  }
}

__global__ __launch_bounds__(512) void bscan_kernel(const int* __restrict__ gbh,
                                                    int* __restrict__ bbase,
                                                    int* __restrict__ bcur,
                                                    int* __restrict__ row_ptr) {
  __shared__ int s[512];
  int t = threadIdx.x;
  int x = (t < NBUCK) ? gbh[t] : 0;
  s[t] = x;
  __syncthreads();
  #pragma unroll
  for (int st = 1; st < 512; st <<= 1) {
    int v = (t >= st) ? s[t - st] : 0;
    __syncthreads();
    s[t] += v;
    __syncthreads();
  }
  if (t < NBUCK) {
    int base = s[t] - x;
    bbase[t] = base;
    bcur[t] = base;
  }
  if (t == 0) {
    bbase[NBUCK] = NNZ;
    row_ptr[NTOT] = NNZ;
  }
}

__global__ __launch_bounds__(256) void binA_kernel(
    const int* __restrict__ row, const int* __restrict__ col,
    const float* __restrict__ val, int* __restrict__ bcur,
    int2* __restrict__ temp) {
  __shared__ int hist[NBUCK];
  __shared__ int base[NBUCK];
  int t = threadIdx.x;
  for (int i = t; i < NBUCK; i += 256) hist[i] = 0;
  __syncthreads();
  int e0 = blockIdx.x * EPB + t;
  int xp[16], yb[16], bk[16], ofs[16];
  #pragma unroll
  for (int i = 0; i < 16; ++i) {
    int e = e0 + i * 256;
    bk[i] = -1;
    if (e < NNZ) {
      int r = row[e];
      int b = r >> 8;
      xp[i] = col[e] | ((r & 255) << 17);
      yb[i] = __float_as_int(val[e]);
      bk[i] = b;
      ofs[i] = atomicAdd(&hist[b], 1);
    }
  }
  __syncthreads();
  for (int i = t; i < NBUCK; i += 256) {
    int h = hist[i];
    base[i] = h ? atomicAdd(&bcur[i], h) : 0;
  }
  __syncthreads();
  #pragma unroll
  for (int i = 0; i < 16; ++i) {
    if (bk[i] >= 0) {
      int2 p; p.x = xp[i]; p.y = yb[i];
      temp[base[bk[i]] + ofs[i]] = p;
    }
  }
}

__global__ __launch_bounds__(1024) void binB2_kernel(
    const int* __restrict__ bbase, const int2* __restrict__ temp,
    int2* __restrict__ epair, int* __restrict__ row_ptr) {
  __shared__ int cnt[256];
  __shared__ int sc[256];
  __shared__ int cur[256];
  int b = blockIdx.x, t = threadIdx.x;
  int r0 = b << 8;
  int nr = min(256, NTOT - r0);
  int lo = bbase[b], hi = bbase[b + 1];
  if (t < 256) cnt[t] = 0;
  __syncthreads();
  for (int i = lo + t; i < hi; i += 1024)
    atomicAdd(&cnt[(temp[i].x >> 17) & 255], 1);
  __syncthreads();
  if (t < 256) sc[t] = cnt[t];
  __syncthreads();
  #pragma unroll
  for (int st = 1; st < 256; st <<= 1) {
    int v = 0;
    if (t < 256 && t >= st) v = sc[t - st];
    __syncthreads();
    if (t < 256) sc[t] += v;
    __syncthreads();
  }
  if (t < nr) {
    int ex = lo + sc[t] - cnt[t];
    row_ptr[r0 + t] = ex;
    cur[t] = ex;
  }
  __syncthreads();
  for (int i = lo + t; i < hi; i += 1024) {
    int2 p = temp[i];
    int rlow = (p.x >> 17) & 255;
    int pos = atomicAdd(&cur[rlow], 1);
    int2 q; q.x = p.x & 0x1FFFF; q.y = p.y;
    epair[pos] = q;
  }
}

// f32 ego -> bf16 shadow
__global__ __launch_bounds__(256) void tobf_kernel(const float4* __restrict__ src,
                                                   ushort4* __restrict__ dst) {
  int i = blockIdx.x * 256 + threadIdx.x;
  if (i < NTOT * D / 4) {
    float4 f = src[i];
    ushort4 o;
    o.x = f2bf(f.x); o.y = f2bf(f.y); o.z = f2bf(f.z); o.w = f2bf(f.w);
    dst[i] = o;
  }
}

// ---------- fused CSR SpMM (bf16-only state, NT epair) + MFMA transform ----------
__global__ __launch_bounds__(512, 8) void spmm_mfma_kernel(
    const int* __restrict__ row_ptr, const int2* __restrict__ epair,
    const unsigned short* __restrict__ bf_in, unsigned short* __restrict__ bf_out,
    const float* __restrict__ Wg, const float* __restrict__ bg,
    const float* __restrict__ Wb, const float* __restrict__ bb) {
  __shared__ unsigned short sW[2][64][72];
  __shared__ unsigned short sSH[2][32][72];
  __shared__ unsigned short sOut[32][68];
  int t = threadIdx.x;
  for (int i = t; i < 4096; i += 512) {
    int rr = i >> 6, cc = i & 63;
    sW[0][rr][cc] = f2bf(Wg[i]);
    sW[1][rr][cc] = f2bf(Wb[i]);
  }

  int lane = t & 63;
  int w = t >> 6;
  int es = lane >> 4;
  int q  = lane & 15;
  const ushort4* bfv = (const ushort4*)bf_in;
  int r0 = blockIdx.x * 32;

  #pragma unroll
  for (int i = 0; i < 4; ++i) {
    int rl = w + 8 * i;
    int r = r0 + rl;
    int rp0 = row_ptr[r], rp1 = row_ptr[r + 1];
    float4 A0 = {0.f, 0.f, 0.f, 0.f}, A1 = A0, A2 = A0, A3 = A0;
    if (rp0 < rp1) {
      int last = rp1 - 1;
      for (int j = rp0; j < rp1; j += 32) {
        int c0i, v0i, c1i, v1i, c2i, v2i, c3i, v3i;
        int c4i, v4i, c5i, v5i, c6i, v6i, c7i, v7i;
        nt_edge(&epair[min(j + es,      last)], c0i, v0i);
        nt_edge(&epair[min(j + 4 + es,  last)], c1i, v1i);
        nt_edge(&epair[min(j + 8 + es,  last)], c2i, v2i);
        nt_edge(&epair[min(j + 12 + es, last)], c3i, v3i);
        nt_edge(&epair[min(j + 16 + es, last)], c4i, v4i);
        nt_edge(&epair[min(j + 20 + es, last)], c5i, v5i);
        nt_edge(&epair[min(j + 24 + es, last)], c6i, v6i);
        nt_edge(&epair[min(j + 28 + es, last)], c7i, v7i);
        ushort4 u0 = bfv[c0i * 16 + q];
        ushort4 u1 = bfv[c1i * 16 + q];
        ushort4 u2 = bfv[c2i * 16 + q];
        ushort4 u3 = bfv[c3i * 16 + q];
        ushort4 u4 = bfv[c4i * 16 + q];
        ushort4 u5 = bfv[c5i * 16 + q];
        ushort4 u6 = bfv[c6i * 16 + q];
        ushort4 u7 = bfv[c7i * 16 + q];
        float v0 = (j + es      < rp1) ? __int_as_float(v0i) : 0.f;
        float v1 = (j + 4 + es  < rp1) ? __int_as_float(v1i) : 0.f;
        float v2 = (j + 8 + es  < rp1) ? __int_as_float(v2i) : 0.f;
        float v3 = (j + 12 + es < rp1) ? __int_as_float(v3i) : 0.f;
        float v4 = (j + 16 + es < rp1) ? __int_as_float(v4i) : 0.f;
        float v5 = (j + 20 + es < rp1) ? __int_as_float(v5i) : 0.f;
        float v6 = (j + 24 + es < rp1) ? __int_as_float(v6i) : 0.f;
        float v7 = (j + 28 + es < rp1) ? __int_as_float(v7i) : 0.f;
        A0.x = fmaf(v0, bf2f(u0.x), A0.x); A0.y = fmaf(v0, bf2f(u0.y), A0.y);
        A0.z = fmaf(v0, bf2f(u0.z), A0.z); A0.w = fmaf(v0, bf2f(u0.w), A0.w);
        A1.x = fmaf(v1, bf2f(u1.x), A1.x); A1.y = fmaf(v1, bf2f(u1.y), A1.y);
        A1.z = fmaf(v1, bf2f(u1.z), A1.z); A1.w = fmaf(v1, bf2f(u1.w), A1.w);
        A2.x = fmaf(v2, bf2f(u2.x), A2.x); A2.y = fmaf(v2, bf2f(u2.y), A2.y);
        A2.z = fmaf(v2, bf2f(u2.z), A2.z); A2.w = fmaf(v2, bf2f(u2.w), A2.w);
        A3.x = fmaf(v3, bf2f(u3.x), A3.x); A3.y = fmaf(v3, bf2f(u3.y), A3.y);
        A3.z = fmaf(v3, bf2f(u3.z), A3.z); A3.w = fmaf(v3, bf2f(u3.w), A3.w);
        A0.x = fmaf(v4, bf2f(u4.x), A0.x); A0.y = fmaf(v4, bf2f(u4.y), A0.y);
        A0.z = fmaf(v4, bf2f(u4.z), A0.z); A0.w = fmaf(v4, bf2f(u4.w), A0.w);
        A1.x = fmaf(v5, bf2f(u5.x), A1.x); A1.y = fmaf(v5, bf2f(u5.y), A1.y);
        A1.z = fmaf(v5, bf2f(u5.z), A1.z); A1.w = fmaf(v5, bf2f(u5.w), A1.w);
        A2.x = fmaf(v6, bf2f(u6.x), A2.x); A2.y = fmaf(v6, bf2f(u6.y), A2.y);
        A2.z = fmaf(v6, bf2f(u6.z), A2.z); A2.w = fmaf(v6, bf2f(u6.w), A2.w);
        A3.x = fmaf(v7, bf2f(u7.x), A3.x); A3.y = fmaf(v7, bf2f(u7.y), A3.y);
        A3.z = fmaf(v7, bf2f(u7.z), A3.z); A3.w = fmaf(v7, bf2f(u7.w), A3.w);
      }
    }
    float4 S;
    S.x = (A0.x + A1.x) + (A2.x + A3.x);
    S.y = (A0.y + A1.y) + (A2.y + A3.y);
    S.z = (A0.z + A1.z) + (A2.z + A3.z);
    S.w = (A0.w + A1.w) + (A2.w + A3.w);
    S.x += __shfl_xor(S.x, 32); S.y += __shfl_xor(S.y, 32);
    S.z += __shfl_xor(S.z, 32); S.w += __shfl_xor(S.w, 32);
    S.x += __shfl_xor(S.x, 16); S.y += __shfl_xor(S.y, 16);
    S.z += __shfl_xor(S.z, 16); S.w += __shfl_xor(S.w, 16);
    if (lane < 16) {
      ushort4 e4 = bfv[r * 16 + q];
      ushort4 sq, hq;
      sq.x = f2bf(S.x); sq.y = f2bf(S.y); sq.z = f2bf(S.z); sq.w = f2bf(S.w);
      hq.x = f2bf(bf2f(e4.x) * S.x); hq.y = f2bf(bf2f(e4.y) * S.y);
      hq.z = f2bf(bf2f(e4.z) * S.z); hq.w = f2bf(bf2f(e4.w) * S.w);
      *(ushort4*)&sSH[0][rl][q * 4] = sq;
      *(ushort4*)&sSH[1][rl][q * 4] = hq;
    }
  }
  __syncthreads();

  int mt = w & 1, ct = w >> 1;
  int ln = lane & 15;
  int kg = lane >> 4;
  int colg = ct * 16 + ln;
  float bias = bg[colg] + bb[colg];
  f32x4 c = {bias, bias, bias, bias};
  const bf16x8 aS0 = *(const bf16x8*)&sSH[0][mt * 16 + ln][kg * 8];
  const bf16x8 aS1 = *(const bf16x8*)&sSH[0][mt * 16 + ln][32 + kg * 8];
  const bf16x8 aH0 = *(const bf16x8*)&sSH[1][mt * 16 + ln][kg * 8];
  const bf16x8 aH1 = *(const bf16x8*)&sSH[1][mt * 16 + ln][32 + kg * 8];
  const bf16x8 bG0 = *(const bf16x8*)&sW[0][colg][kg * 8];
  const bf16x8 bG1 = *(const bf16x8*)&sW[0][colg][32 + kg * 8];
  const bf16x8 bB0 = *(const bf16x8*)&sW[1][colg][kg * 8];
  const bf16x8 bB1 = *(const bf16x8*)&sW[1][colg][32 + kg * 8];
  c = __builtin_amdgcn_mfma_f32_16x16x32_bf16(aS0, bG0, c, 0, 0, 0);
  c = __builtin_amdgcn_mfma_f32_16x16x32_bf16(aS1, bG1, c, 0, 0, 0);
  c = __builtin_amdgcn_mfma_f32_16x16x32_bf16(aH0, bB0, c, 0, 0, 0);
  c = __builtin_amdgcn_mfma_f32_16x16x32_bf16(aH1, bB1, c, 0, 0, 0);
  #pragma unroll
  for (int j2 = 0; j2 < 4; ++j2) {
    int rowl = mt * 16 + kg * 4 + j2;
    sOut[rowl][colg] = f2bf(c[j2]);
  }
  __syncthreads();
  {
    int rowl = t >> 4, ch = t & 15;
    ushort4 o = *(ushort4*)&sOut[rowl][ch * 4];
    ((ushort4*)&bf_out[(size_t)(r0 + rowl) * D])[ch] = o;
  }
}

// ---------- mid-path (f32, per-row hist + scan + scatter) ----------
__global__ __launch_bounds__(256) void hist_kernel(const int* __restrict__ row,
                                                   int* __restrict__ counts) {
  unsigned e = blockIdx.x * 256u + threadIdx.x;
  if (e < NNZ) atomicAdd(&counts[row[e]], 1);
}

__global__ __launch_bounds__(1024) void scanA_kernel(const int* __restrict__ counts,
                                                     int* __restrict__ row_ptr,
                                                     int* __restrict__ blk_sums) {
  __shared__ int s[1024];
  int t = threadIdx.x;
  int gid = blockIdx.x * 1024 + t;
  int x = (gid < NTOT) ? counts[gid] : 0;
  s[t] = x;
  __syncthreads();
  #pragma unroll
  for (int off = 1; off < 1024; off <<= 1) {
    int v = (t >= off) ? s[t - off] : 0;
    __syncthreads();
    s[t] += v;
    __syncthreads();
  }
  if (gid < NTOT) row_ptr[gid] = s[t] - x;
  if (t == 1023) blk_sums[blockIdx.x] = s[t];
}

__global__ __launch_bounds__(128) void scanB_kernel(int* __restrict__ blk_sums,
                                                    int* __restrict__ blk_off) {
  __shared__ int s[128];
  int t = threadIdx.x;
  int x = (t < SCAN_BLOCKS) ? blk_sums[t] : 0;
  s[t] = x;
  __syncthreads();
  #pragma unroll
  for (int off = 1; off < 128; off <<= 1) {
    int v = (t >= off) ? s[t - off] : 0;
    __syncthreads();
    s[t] += v;
    __syncthreads();
  }
  if (t < SCAN_BLOCKS) blk_off[t] = s[t] - x;
}

__global__ __launch_bounds__(1024) void scanC_kernel(int* __restrict__ row_ptr,
                                                     int* __restrict__ cursor,
                                                     const int* __restrict__ blk_off) {
  int gid = blockIdx.x * 1024 + threadIdx.x;
  if (gid < NTOT) {
    int v = row_ptr[gid] + blk_off[blockIdx.x];
    row_ptr[gid] = v;
    cursor[gid] = v;
  }
  if (gid == 0) row_ptr[NTOT] = NNZ;
}

__global__ __launch_bounds__(256) void scatter_kernel(
    const int* __restrict__ row, const int* __restrict__ col,
    const float* __restrict__ val, int* __restrict__ cursor,
    int2* __restrict__ epair) {
  unsigned e = blockIdx.x * 256u + threadIdx.x;
  if (e >= NNZ) return;
  int r = row[e];
  int pos = atomicAdd(&cursor[r], 1);
  int2 p; p.x = col[e]; p.y = __float_as_int(val[e]);
  epair[pos] = p;
}

__global__ __launch_bounds__(1024) void spmm_xform_kernel(
    const int* __restrict__ row_ptr, const int2* __restrict__ epair,
    const float* __restrict__ ego_in, float* __restrict__ ego_out,
    const float* __restrict__ Wg, const float* __restrict__ bg,
    const float* __restrict__ Wb, const float* __restrict__ bb) {
  __shared__ float sWg[64][65];
  __shared__ float sWb[64][65];
  __shared__ float sS[16][64];
  __shared__ float sH[16][64];
  int t = threadIdx.x;
  for (int i = t; i < 4096; i += 1024) {
    sWg[i >> 6][i & 63] = Wg[i];
    sWb[i >> 6][i & 63] = Wb[i];
  }
  __syncthreads();
  int lane = t & 63;
  int w = t >> 6;
  int r = blockIdx.x * 16 + w;
  int rp0 = row_ptr[r], rp1 = row_ptr[r + 1];
  float a0 = 0.f, a1 = 0.f, a2 = 0.f, a3 = 0.f;
  for (int e0 = rp0; e0 < rp1; e0 += 64) {
    int n = rp1 - e0; if (n > 64) n = 64;
    int ce = 0; float ve = 0.f;
    if (lane < n) {
      int2 p = epair[e0 + lane];
      ce = p.x; ve = __int_as_float(p.y);
    }
    int j = 0;
    for (; j + 4 <= n; j += 4) {
      int   c0 = __shfl(ce, j),     c1 = __shfl(ce, j + 1);
      int   c2 = __shfl(ce, j + 2), c3 = __shfl(ce, j + 3);
      float v0 = __shfl(ve, j),     v1 = __shfl(ve, j + 1);
      float v2 = __shfl(ve, j + 2), v3 = __shfl(ve, j + 3);
      float g0 = ego_in[c0 * D + lane], g1 = ego_in[c1 * D + lane];
      float g2 = ego_in[c2 * D + lane], g3 = ego_in[c3 * D + lane];
      a0 = fmaf(v0, g0, a0); a1 = fmaf(v1, g1, a1);
      a2 = fmaf(v2, g2, a2); a3 = fmaf(v3, g3, a3);
    }
    for (; j < n; ++j) {
      int c = __shfl(ce, j); float v = __shfl(ve, j);
      a0 = fmaf(v, ego_in[c * D + lane], a0);
    }
  }
  float s = (a0 + a1) + (a2 + a3);
  float e = ego_in[r * D + lane];
  sS[w][lane] = s;
  sH[w][lane] = e * s;
  float acc = bg[lane] + bb[lane];
  #pragma unroll
  for (int j = 0; j < 64; ++j)
    acc = fmaf(sWg[lane][j], sS[w][j], fmaf(sWb[lane][j], sH[w][j], acc));
  ego_out[r * D + lane] = acc;
}

// ---------- atomic fallback ----------
__global__ __launch_bounds__(256) void spmm_atomic_kernel(
    const int* __restrict__ row, const int* __restrict__ col,
    const float* __restrict__ val, const float* __restrict__ ego,
    float* __restrict__ side) {
  unsigned tid = blockIdx.x * 256u + threadIdx.x;
  unsigned e = tid >> 6, d = tid & 63u;
  if (e >= NNZ) return;
  atomicAdd(&side[row[e] * D + d], val[e] * ego[col[e] * D + d]);
}

__global__ __launch_bounds__(256) void transform_kernel(
    const float* __restrict__ side, float* __restrict__ ego,
    const float* __restrict__ Wg, const float* __restrict__ bg,
    const float* __restrict__ Wb, const float* __restrict__ bb) {
  __shared__ float sWg[64][65];
  __shared__ float sWb[64][65];
  __shared__ float sS[4][64];
  __shared__ float sH[4][64];
  int t = threadIdx.x;
  for (int i = t; i < 4096; i += 256) {
    sWg[i >> 6][i & 63] = Wg[i];
    sWb[i >> 6][i & 63] = Wb[i];
  }
  int w = t >> 6, d = t & 63;
  int r = blockIdx.x * 4 + w;
  float e = 0.f, s = 0.f;
  if (r < NTOT) { e = ego[r * D + d]; s = side[r * D + d]; }
  sS[w][d] = s;
  sH[w][d] = e * s;
  __syncthreads();
  float acc = bg[d] + bb[d];
  #pragma unroll
  for (int j = 0; j < 64; ++j)
    acc = fmaf(sWg[d][j], sS[w][j], fmaf(sWb[d][j], sH[w][j], acc));
  if (r < NTOT) ego[r * D + d] = acc;
}

// ---------- output gathers ----------
__global__ void gather0_kernel(const int* __restrict__ users, const int* __restrict__ pos,
                               const int* __restrict__ neg, const float* __restrict__ ego,
                               float* __restrict__ out) {
  unsigned tid = blockIdx.x * 256u + threadIdx.x;
  unsigned d = tid & 63u, b = (tid >> 6) & 1023u, t = tid >> 16;
  int idx = (t == 0u) ? users[b] : (t == 1u ? N_USERS + pos[b] : N_USERS + neg[b]);
  out[t * (B * 256) + b * 256 + d] = ego[idx * D + d];
}

__global__ void gather_norm_kernel(const int* __restrict__ users, const int* __restrict__ pos,
                                   const int* __restrict__ neg, const float* __restrict__ ego,
                                   float* __restrict__ out, int seg) {
  unsigned tid = blockIdx.x * 256u + threadIdx.x;
  unsigned d = tid & 63u, b = (tid >> 6) & 1023u, t = tid >> 16;
  int idx = (t == 0u) ? users[b] : (t == 1u ? N_USERS + pos[b] : N_USERS + neg[b]);
  float v = ego[idx * D + d];
  float sq = v * v;
  #pragma unroll
  for (int off = 32; off; off >>= 1) sq += __shfl_xor(sq, off);
  float nrm = fmaxf(sqrtf(sq), 1e-12f);
  out[t * (B * 256) + b * 256 + seg * 64 + d] = v / nrm;
}

__global__ void gather_norm_bf_kernel(const int* __restrict__ users, const int* __restrict__ pos,
                                      const int* __restrict__ neg,
                                      const unsigned short* __restrict__ bft,
                                      float* __restrict__ out, int seg) {
  unsigned tid = blockIdx.x * 256u + threadIdx.x;
  unsigned d = tid & 63u, b = (tid >> 6) & 1023u, t = tid >> 16;
  int idx = (t == 0u) ? users[b] : (t == 1u ? N_USERS + pos[b] : N_USERS + neg[b]);
  float v = bf2f(bft[idx * D + d]);
  float sq = v * v;
  #pragma unroll
  for (int off = 32; off; off >>= 1) sq += __shfl_xor(sq, off);
  float nrm = fmaxf(sqrtf(sq), 1e-12f);
  out[t * (B * 256) + b * 256 + seg * 64 + d] = v / nrm;
}

extern "C" void kernel_launch(void* const* d_in, const int* in_sizes, int n_in,
                              void* d_out, int out_size, void* d_ws, size_t ws_size,
                              hipStream_t stream) {
  const int*   users    = (const int*)d_in[0];
  const int*   pos      = (const int*)d_in[1];
  const int*   neg      = (const int*)d_in[2];
  const int*   adj_row  = (const int*)d_in[3];
  const int*   adj_col  = (const int*)d_in[4];
  const float* adj_val  = (const float*)d_in[5];
  const float* user_emb = (const float*)d_in[6];
  const float* item_emb = (const float*)d_in[7];
  const float* gcn_W    = (const float*)d_in[8];
  const float* gcn_b    = (const float*)d_in[9];
  const float* bi_W     = (const float*)d_in[10];
  const float* bi_b     = (const float*)d_in[11];
  float* out = (float*)d_out;

  const size_t EG = (size_t)NTOT * D;

  float* ego0 = (float*)d_ws;
  float* ego1 = ego0 + EG;
  int2*  epair   = (int2*)(ego1 + EG);
  int*   X       = (int*)(epair + NNZ);
  int2*  temp    = (int2*)X;
  unsigned short* bf0 = (unsigned short*)X;
  unsigned short* bf1 = bf0 + EG;
  int*   row_ptr = X + 2 * (size_t)NNZ;
  int*   bcur    = row_ptr + (NTOT + 1);
  int*   bbase   = bcur + NBUCK;          // NBUCK+1
  int*   gbh     = bbase + (NBUCK + 1);   // NBUCK
  const size_t WS_FULL = ((size_t)(2 * EG + 2 * (size_t)NNZ + 2 * (size_t)NNZ
                          + (NTOT + 1) + 3 * NBUCK + 1)) * 4;

  int*   m_row_ptr = (int*)(epair + NNZ);
  int*   m_cursor  = m_row_ptr + (NTOT + 1);
  int*   m_blk     = m_cursor + (NTOT + 1);
  int*   m_counts  = (int*)ego1;
  const size_t WS_MID = ((size_t)(2 * EG + 2 * (size_t)NNZ
                         + 2 * (NTOT + 1) + 2 * SCAN_BLOCKS)) * 4;

  hipMemcpyAsync(ego0, user_emb, (size_t)N_USERS * D * sizeof(float),
                 hipMemcpyDeviceToDevice, stream);
  hipMemcpyAsync(ego0 + (size_t)N_USERS * D, item_emb,
                 (size_t)(NTOT - N_USERS) * D * sizeof(float),
                 hipMemcpyDeviceToDevice, stream);

  gather0_kernel<<<768, 256, 0, stream>>>(users, pos, neg, ego0, out);

  if (ws_size >= WS_FULL) {
    hipMemsetAsync(gbh, 0, NBUCK * sizeof(int), stream);
    bhist_kernel<<<BINA_BLOCKS, 256, 0, stream>>>(adj_row, gbh);
    bscan_kernel<<<1, 512, 0, stream>>>(gbh, bbase, bcur, row_ptr);
    binA_kernel<<<BINA_BLOCKS, 256, 0, stream>>>(adj_row, adj_col, adj_val, bcur, temp);
    binB2_kernel<<<NBUCK, 1024, 0, stream>>>(bbase, temp, epair, row_ptr);
    tobf_kernel<<<(NTOT * D / 4 + 255) / 256, 256, 0, stream>>>((const float4*)ego0,
                                                                (ushort4*)bf0);
    unsigned short* bcurr = bf0;
    unsigned short* bnxt  = bf1;
    for (int k = 0; k < 3; ++k) {
      spmm_mfma_kernel<<<NTOT / 32, 512, 0, stream>>>(
          row_ptr, epair, bcurr, bnxt,
          gcn_W + k * 4096, gcn_b + k * 64, bi_W + k * 4096, bi_b + k * 64);
      gather_norm_bf_kernel<<<768, 256, 0, stream>>>(users, pos, neg, bnxt, out, k + 1);
      unsigned short* tb = bcurr; bcurr = bnxt; bnxt = tb;
    }
  } else if (ws_size >= WS_MID) {
    hipMemsetAsync(m_counts, 0, (size_t)NTOT * sizeof(int), stream);
    hist_kernel<<<(NNZ + 255) / 256, 256, 0, stream>>>(adj_row, m_counts);
    scanA_kernel<<<SCAN_BLOCKS, 1024, 0, stream>>>(m_counts, m_row_ptr, m_blk);
    scanB_kernel<<<1, 128, 0, stream>>>(m_blk, m_blk + SCAN_BLOCKS);
    scanC_kernel<<<SCAN_BLOCKS, 1024, 0, stream>>>(m_row_ptr, m_cursor, m_blk + SCAN_BLOCKS);
    scatter_kernel<<<(NNZ + 255) / 256, 256, 0, stream>>>(adj_row, adj_col, adj_val,
                                                          m_cursor, epair);
    float* cur = ego0;
    float* nxt = ego1;
    for (int k = 0; k < 3; ++k) {
      spmm_xform_kernel<<<NTOT / 16, 1024, 0, stream>>>(
          m_row_ptr, epair, cur, nxt,
          gcn_W + k * 4096, gcn_b + k * 64, bi_W + k * 4096, bi_b + k * 64);
      gather_norm_kernel<<<768, 256, 0, stream>>>(users, pos, neg, nxt, out, k + 1);
      float* tf = cur; cur = nxt; nxt = tf;
    }
  } else {
    float* side = ego1;
    for (int k = 0; k < 3; ++k) {
      hipMemsetAsync(side, 0, (size_t)NTOT * D * sizeof(float), stream);
      spmm_atomic_kernel<<<(NNZ * 64) / 256, 256, 0, stream>>>(adj_row, adj_col, adj_val,
                                                               ego0, side);
      transform_kernel<<<(NTOT + 3) / 4, 256, 0, stream>>>(
          side, ego0, gcn_W + k * 4096, gcn_b + k * 64, bi_W + k * 4096, bi_b + k * 64);
      gather_norm_kernel<<<768, 256, 0, stream>>>(users, pos, neg, ego0, out, k + 1);
    }
  }
}

// Round 16
// 437.465 us; speedup vs baseline: 9.6451x; 1.1543x over previous
//
#include <hip/hip_runtime.h>

#define N_USERS 50000
#define NTOT    100000
#define D       64
#define NNZ     3200000
#define B       1024
#define SCAN_BLOCKS ((NTOT + 1023) / 1024)   // 98
#define NBUCK ((NTOT + 255) / 256)           // 391
#define EPB 4096
#define BINA_BLOCKS ((NNZ + EPB - 1) / EPB)  // 782

typedef __attribute__((ext_vector_type(8))) short bf16x8;
typedef __attribute__((ext_vector_type(4))) float f32x4;

__device__ __forceinline__ unsigned short f2bf(float f) {
  unsigned u = __float_as_uint(f);
  unsigned r = (u + 0x7FFFu + ((u >> 16) & 1u)) >> 16;
  return (unsigned short)r;
}
__device__ __forceinline__ float bf2f(unsigned short s) {
  return __uint_as_float(((unsigned)s) << 16);
}

// ---------- bucket-level CSR build ----------
__global__ __launch_bounds__(256) void bhist_kernel(const int* __restrict__ row,
                                                    int* __restrict__ gbh) {
  __shared__ int h[NBUCK];
  int t = threadIdx.x;
  for (int i = t; i < NBUCK; i += 256) h[i] = 0;
  __syncthreads();
  int e0 = blockIdx.x * EPB + t;
  #pragma unroll
  for (int i = 0; i < 16; ++i) {
    int e = e0 + i * 256;
    if (e < NNZ) atomicAdd(&h[row[e] >> 8], 1);
  }
  __syncthreads();
  for (int i = t; i < NBUCK; i += 256) {
    int v = h[i];
    if (v) atomicAdd(&gbh[i], v);
  }
}

__global__ __launch_bounds__(512) void bscan_kernel(const int* __restrict__ gbh,
                                                    int* __restrict__ bbase,
                                                    int* __restrict__ bcur,
                                                    int* __restrict__ row_ptr) {
  __shared__ int s[512];
  int t = threadIdx.x;
  int x = (t < NBUCK) ? gbh[t] : 0;
  s[t] = x;
  __syncthreads();
  #pragma unroll
  for (int st = 1; st < 512; st <<= 1) {
    int v = (t >= st) ? s[t - st] : 0;
    __syncthreads();
    s[t] += v;
    __syncthreads();
  }
  if (t < NBUCK) {
    int base = s[t] - x;
    bbase[t] = base;
    bcur[t] = base;
  }
  if (t == 0) {
    bbase[NBUCK] = NNZ;
    row_ptr[NTOT] = NNZ;
  }
}

__global__ __launch_bounds__(256) void binA_kernel(
    const int* __restrict__ row, const int* __restrict__ col,
    const float* __restrict__ val, int* __restrict__ bcur,
    int2* __restrict__ temp) {
  __shared__ int hist[NBUCK];
  __shared__ int base[NBUCK];
  int t = threadIdx.x;
  for (int i = t; i < NBUCK; i += 256) hist[i] = 0;
  __syncthreads();
  int e0 = blockIdx.x * EPB + t;
  int xp[16], yb[16], bk[16], ofs[16];
  #pragma unroll
  for (int i = 0; i < 16; ++i) {
    int e = e0 + i * 256;
    bk[i] = -1;
    if (e < NNZ) {
      int r = row[e];
      int b = r >> 8;
      xp[i] = col[e] | ((r & 255) << 17);
      yb[i] = __float_as_int(val[e]);
      bk[i] = b;
      ofs[i] = atomicAdd(&hist[b], 1);
    }
  }
  __syncthreads();
  for (int i = t; i < NBUCK; i += 256) {
    int h = hist[i];
    base[i] = h ? atomicAdd(&bcur[i], h) : 0;
  }
  __syncthreads();
  #pragma unroll
  for (int i = 0; i < 16; ++i) {
    if (bk[i] >= 0) {
      int2 p; p.x = xp[i]; p.y = yb[i];
      temp[base[bk[i]] + ofs[i]] = p;
    }
  }
}

__global__ __launch_bounds__(1024) void binB2_kernel(
    const int* __restrict__ bbase, const int2* __restrict__ temp,
    int2* __restrict__ epair, int* __restrict__ row_ptr) {
  __shared__ int cnt[256];
  __shared__ int sc[256];
  __shared__ int cur[256];
  int b = blockIdx.x, t = threadIdx.x;
  int r0 = b << 8;
  int nr = min(256, NTOT - r0);
  int lo = bbase[b], hi = bbase[b + 1];
  if (t < 256) cnt[t] = 0;
  __syncthreads();
  for (int i = lo + t; i < hi; i += 1024)
    atomicAdd(&cnt[(temp[i].x >> 17) & 255], 1);
  __syncthreads();
  if (t < 256) sc[t] = cnt[t];
  __syncthreads();
  #pragma unroll
  for (int st = 1; st < 256; st <<= 1) {
    int v = 0;
    if (t < 256 && t >= st) v = sc[t - st];
    __syncthreads();
    if (t < 256) sc[t] += v;
    __syncthreads();
  }
  if (t < nr) {
    int ex = lo + sc[t] - cnt[t];
    row_ptr[r0 + t] = ex;
    cur[t] = ex;
  }
  __syncthreads();
  for (int i = lo + t; i < hi; i += 1024) {
    int2 p = temp[i];
    int rlow = (p.x >> 17) & 255;
    int pos = atomicAdd(&cur[rlow], 1);
    int2 q; q.x = p.x & 0x1FFFF; q.y = p.y;
    epair[pos] = q;
  }
}

// f32 ego -> bf16 shadow
__global__ __launch_bounds__(256) void tobf_kernel(const float4* __restrict__ src,
                                                   ushort4* __restrict__ dst) {
  int i = blockIdx.x * 256 + threadIdx.x;
  if (i < NTOT * D / 4) {
    float4 f = src[i];
    ushort4 o;
    o.x = f2bf(f.x); o.y = f2bf(f.y); o.z = f2bf(f.z); o.w = f2bf(f.w);
    dst[i] = o;
  }
}

// ---------- fused CSR SpMM (bf16-only state) + MFMA transform ----------
__global__ __launch_bounds__(512, 8) void spmm_mfma_kernel(
    const int* __restrict__ row_ptr, const int2* __restrict__ epair,
    const unsigned short* __restrict__ bf_in, unsigned short* __restrict__ bf_out,
    const float* __restrict__ Wg, const float* __restrict__ bg,
    const float* __restrict__ Wb, const float* __restrict__ bb) {
  __shared__ unsigned short sW[2][64][72];
  __shared__ unsigned short sSH[2][32][72];
  __shared__ unsigned short sOut[32][68];
  int t = threadIdx.x;
  for (int i = t; i < 4096; i += 512) {
    int rr = i >> 6, cc = i & 63;
    sW[0][rr][cc] = f2bf(Wg[i]);
    sW[1][rr][cc] = f2bf(Wb[i]);
  }

  int lane = t & 63;
  int w = t >> 6;
  int es = lane >> 4;
  int q  = lane & 15;
  const ushort4* bfv = (const ushort4*)bf_in;
  int r0 = blockIdx.x * 32;

  #pragma unroll
  for (int i = 0; i < 4; ++i) {
    int rl = w + 8 * i;
    int r = r0 + rl;
    int rp0 = row_ptr[r], rp1 = row_ptr[r + 1];
    float4 A0 = {0.f, 0.f, 0.f, 0.f}, A1 = A0, A2 = A0, A3 = A0;
    if (rp0 < rp1) {
      int last = rp1 - 1;
      for (int j = rp0; j < rp1; j += 32) {
        int2 p0 = epair[min(j + es,      last)];
        int2 p1 = epair[min(j + 4 + es,  last)];
        int2 p2 = epair[min(j + 8 + es,  last)];
        int2 p3 = epair[min(j + 12 + es, last)];
        int2 p4 = epair[min(j + 16 + es, last)];
        int2 p5 = epair[min(j + 20 + es, last)];
        int2 p6 = epair[min(j + 24 + es, last)];
        int2 p7 = epair[min(j + 28 + es, last)];
        ushort4 u0 = bfv[p0.x * 16 + q];
        ushort4 u1 = bfv[p1.x * 16 + q];
        ushort4 u2 = bfv[p2.x * 16 + q];
        ushort4 u3 = bfv[p3.x * 16 + q];
        ushort4 u4 = bfv[p4.x * 16 + q];
        ushort4 u5 = bfv[p5.x * 16 + q];
        ushort4 u6 = bfv[p6.x * 16 + q];
        ushort4 u7 = bfv[p7.x * 16 + q];
        float v0 = (j + es      < rp1) ? __int_as_float(p0.y) : 0.f;
        float v1 = (j + 4 + es  < rp1) ? __int_as_float(p1.y) : 0.f;
        float v2 = (j + 8 + es  < rp1) ? __int_as_float(p2.y) : 0.f;
        float v3 = (j + 12 + es < rp1) ? __int_as_float(p3.y) : 0.f;
        float v4 = (j + 16 + es < rp1) ? __int_as_float(p4.y) : 0.f;
        float v5 = (j + 20 + es < rp1) ? __int_as_float(p5.y) : 0.f;
        float v6 = (j + 24 + es < rp1) ? __int_as_float(p6.y) : 0.f;
        float v7 = (j + 28 + es < rp1) ? __int_as_float(p7.y) : 0.f;
        A0.x = fmaf(v0, bf2f(u0.x), A0.x); A0.y = fmaf(v0, bf2f(u0.y), A0.y);
        A0.z = fmaf(v0, bf2f(u0.z), A0.z); A0.w = fmaf(v0, bf2f(u0.w), A0.w);
        A1.x = fmaf(v1, bf2f(u1.x), A1.x); A1.y = fmaf(v1, bf2f(u1.y), A1.y);
        A1.z = fmaf(v1, bf2f(u1.z), A1.z); A1.w = fmaf(v1, bf2f(u1.w), A1.w);
        A2.x = fmaf(v2, bf2f(u2.x), A2.x); A2.y = fmaf(v2, bf2f(u2.y), A2.y);
        A2.z = fmaf(v2, bf2f(u2.z), A2.z); A2.w = fmaf(v2, bf2f(u2.w), A2.w);
        A3.x = fmaf(v3, bf2f(u3.x), A3.x); A3.y = fmaf(v3, bf2f(u3.y), A3.y);
        A3.z = fmaf(v3, bf2f(u3.z), A3.z); A3.w = fmaf(v3, bf2f(u3.w), A3.w);
        A0.x = fmaf(v4, bf2f(u4.x), A0.x); A0.y = fmaf(v4, bf2f(u4.y), A0.y);
        A0.z = fmaf(v4, bf2f(u4.z), A0.z); A0.w = fmaf(v4, bf2f(u4.w), A0.w);
        A1.x = fmaf(v5, bf2f(u5.x), A1.x); A1.y = fmaf(v5, bf2f(u5.y), A1.y);
        A1.z = fmaf(v5, bf2f(u5.z), A1.z); A1.w = fmaf(v5, bf2f(u5.w), A1.w);
        A2.x = fmaf(v6, bf2f(u6.x), A2.x); A2.y = fmaf(v6, bf2f(u6.y), A2.y);
        A2.z = fmaf(v6, bf2f(u6.z), A2.z); A2.w = fmaf(v6, bf2f(u6.w), A2.w);
        A3.x = fmaf(v7, bf2f(u7.x), A3.x); A3.y = fmaf(v7, bf2f(u7.y), A3.y);
        A3.z = fmaf(v7, bf2f(u7.z), A3.z); A3.w = fmaf(v7, bf2f(u7.w), A3.w);
      }
    }
    float4 S;
    S.x = (A0.x + A1.x) + (A2.x + A3.x);
    S.y = (A0.y + A1.y) + (A2.y + A3.y);
    S.z = (A0.z + A1.z) + (A2.z + A3.z);
    S.w = (A0.w + A1.w) + (A2.w + A3.w);
    S.x += __shfl_xor(S.x, 32); S.y += __shfl_xor(S.y, 32);
    S.z += __shfl_xor(S.z, 32); S.w += __shfl_xor(S.w, 32);
    S.x += __shfl_xor(S.x, 16); S.y += __shfl_xor(S.y, 16);
    S.z += __shfl_xor(S.z, 16); S.w += __shfl_xor(S.w, 16);
    if (lane < 16) {
      ushort4 e4 = bfv[r * 16 + q];
      ushort4 sq, hq;
      sq.x = f2bf(S.x); sq.y = f2bf(S.y); sq.z = f2bf(S.z); sq.w = f2bf(S.w);
      hq.x = f2bf(bf2f(e4.x) * S.x); hq.y = f2bf(bf2f(e4.y) * S.y);
      hq.z = f2bf(bf2f(e4.z) * S.z); hq.w = f2bf(bf2f(e4.w) * S.w);
      *(ushort4*)&sSH[0][rl][q * 4] = sq;
      *(ushort4*)&sSH[1][rl][q * 4] = hq;
    }
  }
  __syncthreads();

  int mt = w & 1, ct = w >> 1;
  int ln = lane & 15;
  int kg = lane >> 4;
  int colg = ct * 16 + ln;
  float bias = bg[colg] + bb[colg];
  f32x4 c = {bias, bias, bias, bias};
  const bf16x8 aS0 = *(const bf16x8*)&sSH[0][mt * 16 + ln][kg * 8];
  const bf16x8 aS1 = *(const bf16x8*)&sSH[0][mt * 16 + ln][32 + kg * 8];
  const bf16x8 aH0 = *(const bf16x8*)&sSH[1][mt * 16 + ln][kg * 8];
  const bf16x8 aH1 = *(const bf16x8*)&sSH[1][mt * 16 + ln][32 + kg * 8];
  const bf16x8 bG0 = *(const bf16x8*)&sW[0][colg][kg * 8];
  const bf16x8 bG1 = *(const bf16x8*)&sW[0][colg][32 + kg * 8];
  const bf16x8 bB0 = *(const bf16x8*)&sW[1][colg][kg * 8];
  const bf16x8 bB1 = *(const bf16x8*)&sW[1][colg][32 + kg * 8];
  c = __builtin_amdgcn_mfma_f32_16x16x32_bf16(aS0, bG0, c, 0, 0, 0);
  c = __builtin_amdgcn_mfma_f32_16x16x32_bf16(aS1, bG1, c, 0, 0, 0);
  c = __builtin_amdgcn_mfma_f32_16x16x32_bf16(aH0, bB0, c, 0, 0, 0);
  c = __builtin_amdgcn_mfma_f32_16x16x32_bf16(aH1, bB1, c, 0, 0, 0);
  #pragma unroll
  for (int j2 = 0; j2 < 4; ++j2) {
    int rowl = mt * 16 + kg * 4 + j2;
    sOut[rowl][colg] = f2bf(c[j2]);
  }
  __syncthreads();
  {
    int rowl = t >> 4, ch = t & 15;
    ushort4 o = *(ushort4*)&sOut[rowl][ch * 4];
    ((ushort4*)&bf_out[(size_t)(r0 + rowl) * D])[ch] = o;
  }
}

// ---------- mid-path (f32, per-row hist + scan + scatter) ----------
__global__ __launch_bounds__(256) void hist_kernel(const int* __restrict__ row,
                                                   int* __restrict__ counts) {
  unsigned e = blockIdx.x * 256u + threadIdx.x;
  if (e < NNZ) atomicAdd(&counts[row[e]], 1);
}

__global__ __launch_bounds__(1024) void scanA_kernel(const int* __restrict__ counts,
                                                     int* __restrict__ row_ptr,
                                                     int* __restrict__ blk_sums) {
  __shared__ int s[1024];
  int t = threadIdx.x;
  int gid = blockIdx.x * 1024 + t;
  int x = (gid < NTOT) ? counts[gid] : 0;
  s[t] = x;
  __syncthreads();
  #pragma unroll
  for (int off = 1; off < 1024; off <<= 1) {
    int v = (t >= off) ? s[t - off] : 0;
    __syncthreads();
    s[t] += v;
    __syncthreads();
  }
  if (gid < NTOT) row_ptr[gid] = s[t] - x;
  if (t == 1023) blk_sums[blockIdx.x] = s[t];
}

__global__ __launch_bounds__(128) void scanB_kernel(int* __restrict__ blk_sums,
                                                    int* __restrict__ blk_off) {
  __shared__ int s[128];
  int t = threadIdx.x;
  int x = (t < SCAN_BLOCKS) ? blk_sums[t] : 0;
  s[t] = x;
  __syncthreads();
  #pragma unroll
  for (int off = 1; off < 128; off <<= 1) {
    int v = (t >= off) ? s[t - off] : 0;
    __syncthreads();
    s[t] += v;
    __syncthreads();
  }
  if (t < SCAN_BLOCKS) blk_off[t] = s[t] - x;
}

__global__ __launch_bounds__(1024) void scanC_kernel(int* __restrict__ row_ptr,
                                                     int* __restrict__ cursor,
                                                     const int* __restrict__ blk_off) {
  int gid = blockIdx.x * 1024 + threadIdx.x;
  if (gid < NTOT) {
    int v = row_ptr[gid] + blk_off[blockIdx.x];
    row_ptr[gid] = v;
    cursor[gid] = v;
  }
  if (gid == 0) row_ptr[NTOT] = NNZ;
}

__global__ __launch_bounds__(256) void scatter_kernel(
    const int* __restrict__ row, const int* __restrict__ col,
    const float* __restrict__ val, int* __restrict__ cursor,
    int2* __restrict__ epair) {
  unsigned e = blockIdx.x * 256u + threadIdx.x;
  if (e >= NNZ) return;
  int r = row[e];
  int pos = atomicAdd(&cursor[r], 1);
  int2 p; p.x = col[e]; p.y = __float_as_int(val[e]);
  epair[pos] = p;
}

__global__ __launch_bounds__(1024) void spmm_xform_kernel(
    const int* __restrict__ row_ptr, const int2* __restrict__ epair,
    const float* __restrict__ ego_in, float* __restrict__ ego_out,
    const float* __restrict__ Wg, const float* __restrict__ bg,
    const float* __restrict__ Wb, const float* __restrict__ bb) {
  __shared__ float sWg[64][65];
  __shared__ float sWb[64][65];
  __shared__ float sS[16][64];
  __shared__ float sH[16][64];
  int t = threadIdx.x;
  for (int i = t; i < 4096; i += 1024) {
    sWg[i >> 6][i & 63] = Wg[i];
    sWb[i >> 6][i & 63] = Wb[i];
  }
  __syncthreads();
  int lane = t & 63;
  int w = t >> 6;
  int r = blockIdx.x * 16 + w;
  int rp0 = row_ptr[r], rp1 = row_ptr[r + 1];
  float a0 = 0.f, a1 = 0.f, a2 = 0.f, a3 = 0.f;
  for (int e0 = rp0; e0 < rp1; e0 += 64) {
    int n = rp1 - e0; if (n > 64) n = 64;
    int ce = 0; float ve = 0.f;
    if (lane < n) {
      int2 p = epair[e0 + lane];
      ce = p.x; ve = __int_as_float(p.y);
    }
    int j = 0;
    for (; j + 4 <= n; j += 4) {
      int   c0 = __shfl(ce, j),     c1 = __shfl(ce, j + 1);
      int   c2 = __shfl(ce, j + 2), c3 = __shfl(ce, j + 3);
      float v0 = __shfl(ve, j),     v1 = __shfl(ve, j + 1);
      float v2 = __shfl(ve, j + 2), v3 = __shfl(ve, j + 3);
      float g0 = ego_in[c0 * D + lane], g1 = ego_in[c1 * D + lane];
      float g2 = ego_in[c2 * D + lane], g3 = ego_in[c3 * D + lane];
      a0 = fmaf(v0, g0, a0); a1 = fmaf(v1, g1, a1);
      a2 = fmaf(v2, g2, a2); a3 = fmaf(v3, g3, a3);
    }
    for (; j < n; ++j) {
      int c = __shfl(ce, j); float v = __shfl(ve, j);
      a0 = fmaf(v, ego_in[c * D + lane], a0);
    }
  }
  float s = (a0 + a1) + (a2 + a3);
  float e = ego_in[r * D + lane];
  sS[w][lane] = s;
  sH[w][lane] = e * s;
  float acc = bg[lane] + bb[lane];
  #pragma unroll
  for (int j = 0; j < 64; ++j)
    acc = fmaf(sWg[lane][j], sS[w][j], fmaf(sWb[lane][j], sH[w][j], acc));
  ego_out[r * D + lane] = acc;
}

// ---------- atomic fallback ----------
__global__ __launch_bounds__(256) void spmm_atomic_kernel(
    const int* __restrict__ row, const int* __restrict__ col,
    const float* __restrict__ val, const float* __restrict__ ego,
    float* __restrict__ side) {
  unsigned tid = blockIdx.x * 256u + threadIdx.x;
  unsigned e = tid >> 6, d = tid & 63u;
  if (e >= NNZ) return;
  atomicAdd(&side[row[e] * D + d], val[e] * ego[col[e] * D + d]);
}

__global__ __launch_bounds__(256) void transform_kernel(
    const float* __restrict__ side, float* __restrict__ ego,
    const float* __restrict__ Wg, const float* __restrict__ bg,
    const float* __restrict__ Wb, const float* __restrict__ bb) {
  __shared__ float sWg[64][65];
  __shared__ float sWb[64][65];
  __shared__ float sS[4][64];
  __shared__ float sH[4][64];
  int t = threadIdx.x;
  for (int i = t; i < 4096; i += 256) {
    sWg[i >> 6][i & 63] = Wg[i];
    sWb[i >> 6][i & 63] = Wb[i];
  }
  int w = t >> 6, d = t & 63;
  int r = blockIdx.x * 4 + w;
  float e = 0.f, s = 0.f;
  if (r < NTOT) { e = ego[r * D + d]; s = side[r * D + d]; }
  sS[w][d] = s;
  sH[w][d] = e * s;
  __syncthreads();
  float acc = bg[d] + bb[d];
  #pragma unroll
  for (int j = 0; j < 64; ++j)
    acc = fmaf(sWg[d][j], sS[w][j], fmaf(sWb[d][j], sH[w][j], acc));
  if (r < NTOT) ego[r * D + d] = acc;
}

// ---------- output gathers ----------
__global__ void gather0_kernel(const int* __restrict__ users, const int* __restrict__ pos,
                               const int* __restrict__ neg, const float* __restrict__ ego,
                               float* __restrict__ out) {
  unsigned tid = blockIdx.x * 256u + threadIdx.x;
  unsigned d = tid & 63u, b = (tid >> 6) & 1023u, t = tid >> 16;
  int idx = (t == 0u) ? users[b] : (t == 1u ? N_USERS + pos[b] : N_USERS + neg[b]);
  out[t * (B * 256) + b * 256 + d] = ego[idx * D + d];
}

__global__ void gather_norm_kernel(const int* __restrict__ users, const int* __restrict__ pos,
                                   const int* __restrict__ neg, const float* __restrict__ ego,
                                   float* __restrict__ out, int seg) {
  unsigned tid = blockIdx.x * 256u + threadIdx.x;
  unsigned d = tid & 63u, b = (tid >> 6) & 1023u, t = tid >> 16;
  int idx = (t == 0u) ? users[b] : (t == 1u ? N_USERS + pos[b] : N_USERS + neg[b]);
  float v = ego[idx * D + d];
  float sq = v * v;
  #pragma unroll
  for (int off = 32; off; off >>= 1) sq += __shfl_xor(sq, off);
  float nrm = fmaxf(sqrtf(sq), 1e-12f);
  out[t * (B * 256) + b * 256 + seg * 64 + d] = v / nrm;
}

__global__ void gather_norm_bf_kernel(const int* __restrict__ users, const int* __restrict__ pos,
                                      const int* __restrict__ neg,
                                      const unsigned short* __restrict__ bft,
                                      float* __restrict__ out, int seg) {
  unsigned tid = blockIdx.x * 256u + threadIdx.x;
  unsigned d = tid & 63u, b = (tid >> 6) & 1023u, t = tid >> 16;
  int idx = (t == 0u) ? users[b] : (t == 1u ? N_USERS + pos[b] : N_USERS + neg[b]);
  float v = bf2f(bft[idx * D + d]);
  float sq = v * v;
  #pragma unroll
  for (int off = 32; off; off >>= 1) sq += __shfl_xor(sq, off);
  float nrm = fmaxf(sqrtf(sq), 1e-12f);
  out[t * (B * 256) + b * 256 + seg * 64 + d] = v / nrm;
}

extern "C" void kernel_launch(void* const* d_in, const int* in_sizes, int n_in,
                              void* d_out, int out_size, void* d_ws, size_t ws_size,
                              hipStream_t stream) {
  const int*   users    = (const int*)d_in[0];
  const int*   pos      = (const int*)d_in[1];
  const int*   neg      = (const int*)d_in[2];
  const int*   adj_row  = (const int*)d_in[3];
  const int*   adj_col  = (const int*)d_in[4];
  const float* adj_val  = (const float*)d_in[5];
  const float* user_emb = (const float*)d_in[6];
  const float* item_emb = (const float*)d_in[7];
  const float* gcn_W    = (const float*)d_in[8];
  const float* gcn_b    = (const float*)d_in[9];
  const float* bi_W     = (const float*)d_in[10];
  const float* bi_b     = (const float*)d_in[11];
  float* out = (float*)d_out;

  const size_t EG = (size_t)NTOT * D;

  float* ego0 = (float*)d_ws;
  float* ego1 = ego0 + EG;
  int2*  epair   = (int2*)(ego1 + EG);
  int*   X       = (int*)(epair + NNZ);
  int2*  temp    = (int2*)X;
  unsigned short* bf0 = (unsigned short*)X;
  unsigned short* bf1 = bf0 + EG;
  int*   row_ptr = X + 2 * (size_t)NNZ;
  int*   bcur    = row_ptr + (NTOT + 1);
  int*   bbase   = bcur + NBUCK;          // NBUCK+1
  int*   gbh     = bbase + (NBUCK + 1);   // NBUCK
  const size_t WS_FULL = ((size_t)(2 * EG + 2 * (size_t)NNZ + 2 * (size_t)NNZ
                          + (NTOT + 1) + 3 * NBUCK + 1)) * 4;

  int*   m_row_ptr = (int*)(epair + NNZ);
  int*   m_cursor  = m_row_ptr + (NTOT + 1);
  int*   m_blk     = m_cursor + (NTOT + 1);
  int*   m_counts  = (int*)ego1;
  const size_t WS_MID = ((size_t)(2 * EG + 2 * (size_t)NNZ
                         + 2 * (NTOT + 1) + 2 * SCAN_BLOCKS)) * 4;

  hipMemcpyAsync(ego0, user_emb, (size_t)N_USERS * D * sizeof(float),
                 hipMemcpyDeviceToDevice, stream);
  hipMemcpyAsync(ego0 + (size_t)N_USERS * D, item_emb,
                 (size_t)(NTOT - N_USERS) * D * sizeof(float),
                 hipMemcpyDeviceToDevice, stream);

  gather0_kernel<<<768, 256, 0, stream>>>(users, pos, neg, ego0, out);

  if (ws_size >= WS_FULL) {
    hipMemsetAsync(gbh, 0, NBUCK * sizeof(int), stream);
    bhist_kernel<<<BINA_BLOCKS, 256, 0, stream>>>(adj_row, gbh);
    bscan_kernel<<<1, 512, 0, stream>>>(gbh, bbase, bcur, row_ptr);
    binA_kernel<<<BINA_BLOCKS, 256, 0, stream>>>(adj_row, adj_col, adj_val, bcur, temp);
    binB2_kernel<<<NBUCK, 1024, 0, stream>>>(bbase, temp, epair, row_ptr);
    tobf_kernel<<<(NTOT * D / 4 + 255) / 256, 256, 0, stream>>>((const float4*)ego0,
                                                                (ushort4*)bf0);
    unsigned short* bcurr = bf0;
    unsigned short* bnxt  = bf1;
    for (int k = 0; k < 3; ++k) {
      spmm_mfma_kernel<<<NTOT / 32, 512, 0, stream>>>(
          row_ptr, epair, bcurr, bnxt,
          gcn_W + k * 4096, gcn_b + k * 64, bi_W + k * 4096, bi_b + k * 64);
      gather_norm_bf_kernel<<<768, 256, 0, stream>>>(users, pos, neg, bnxt, out, k + 1);
      unsigned short* tb = bcurr; bcurr = bnxt; bnxt = tb;
    }
  } else if (ws_size >= WS_MID) {
    hipMemsetAsync(m_counts, 0, (size_t)NTOT * sizeof(int), stream);
    hist_kernel<<<(NNZ + 255) / 256, 256, 0, stream>>>(adj_row, m_counts);
    scanA_kernel<<<SCAN_BLOCKS, 1024, 0, stream>>>(m_counts, m_row_ptr, m_blk);
    scanB_kernel<<<1, 128, 0, stream>>>(m_blk, m_blk + SCAN_BLOCKS);
    scanC_kernel<<<SCAN_BLOCKS, 1024, 0, stream>>>(m_row_ptr, m_cursor, m_blk + SCAN_BLOCKS);
    scatter_kernel<<<(NNZ + 255) / 256, 256, 0, stream>>>(adj_row, adj_col, adj_val,
                                                          m_cursor, epair);
    float* cur = ego0;
    float* nxt = ego1;
    for (int k = 0; k < 3; ++k) {
      spmm_xform_kernel<<<NTOT / 16, 1024, 0, stream>>>(
          m_row_ptr, epair, cur, nxt,
          gcn_W + k * 4096, gcn_b + k * 64, bi_W + k * 4096, bi_b + k * 64);
      gather_norm_kernel<<<768, 256, 0, stream>>>(users, pos, neg, nxt, out, k + 1);
      float* tf = cur; cur = nxt; nxt = tf;
    }
  } else {
    float* side = ego1;
    for (int k = 0; k < 3; ++k) {
      hipMemsetAsync(side, 0, (size_t)NTOT * D * sizeof(float), stream);
      spmm_atomic_kernel<<<(NNZ * 64) / 256, 256, 0, stream>>>(adj_row, adj_col, adj_val,
                                                               ego0, side);
      transform_kernel<<<(NTOT + 3) / 4, 256, 0, stream>>>(
          side, ego0, gcn_W + k * 4096, gcn_b + k * 64, bi_W + k * 4096, bi_b + k * 64);
      gather_norm_kernel<<<768, 256, 0, stream>>>(users, pos, neg, ego0, out, k + 1);
    }
  }
}